// Round 5
// baseline (391.025 us; speedup 1.0000x reference)
//
#include <hip/hip_runtime.h>

// FeatureDecorr: group whitening via Newton-Schulz isqrt of 16x16 group covariance.
// x: (32, 256, 56, 56) fp32. Group g = c % 16; "plane-set" p = (n, c/16): 16
// contiguous channel planes of 3136 floats each.
//
// 3 kernels:
//  1) fd_stats:  one read of x -> per-block partial {16 sums, 136 upper-tri products}
//  2) fd_newton: reduce partials, build cov = S2/M - mean mean^T + eps I,
//                Newton-Schulz 10 iters on 16x16 in LDS, emit D and offset = D@mean
//  3) fd_whiten: out[g] = sum_j Dw[g][j]*x[j] + shift[g]   (weight/bias folded)

constexpr int kC    = 256;
constexpr int kHW   = 3136;   // 56*56
constexpr int kP    = 512;    // N * (C/G) = 32*16 plane-sets
constexpr int kAcc  = 152;    // 16 sums + 136 upper-tri products
constexpr float kEps = 1e-5f;
constexpr int kNsIter = 10;

// ---- DPP wave64 float sum (VALU-rate; avoids 912 DS-pipe shuffles per wave) ----
// ctrl/row_mask must be integer constant expressions -> template parameters.
template <int Ctrl, int RowMask>
__device__ __forceinline__ float dpp_fadd(float x) {
  int perm = __builtin_amdgcn_update_dpp(0, __float_as_int(x), Ctrl, RowMask, 0xf, true);
  return x + __int_as_float(perm);
}
__device__ __forceinline__ float wave_sum64(float x) {
  x = dpp_fadd<0xB1, 0xF>(x);   // quad_perm [1,0,3,2]  (xor 1)
  x = dpp_fadd<0x4E, 0xF>(x);   // quad_perm [2,3,0,1]  (xor 2)
  x = dpp_fadd<0x124, 0xF>(x);  // row_ror:4
  x = dpp_fadd<0x128, 0xF>(x);  // row_ror:8 -> all 16 lanes of row have row sum
  x = dpp_fadd<0x142, 0xA>(x);  // row_bcast15 -> rows 1,3 accumulate rows 0,2
  x = dpp_fadd<0x143, 0xC>(x);  // row_bcast31 -> lane 63 = full wave sum
  return x;
}

// ---------------- kernel 1: statistics (one streaming read of x) ----------------
__global__ __launch_bounds__(256, 2) void fd_stats(const float* __restrict__ x,
                                                   float* __restrict__ partials) {
  const int p  = blockIdx.x;
  const int n  = p >> 4, c1 = p & 15;
  const float* base = x + (size_t)(n * kC + c1 * 16) * kHW;
  const int t = threadIdx.x;

  float s[16];
  float pr[136];
#pragma unroll
  for (int j = 0; j < 16; ++j) s[j] = 0.f;
#pragma unroll
  for (int a = 0; a < 136; ++a) pr[a] = 0.f;

  // 1568 float2 chunks per channel plane; 16 channel planes per p.
  for (int ch = t; ch < kHW / 2; ch += 256) {
    float2 v[16];
#pragma unroll
    for (int j = 0; j < 16; ++j)
      v[j] = reinterpret_cast<const float2*>(base + j * kHW)[ch];
#pragma unroll
    for (int j = 0; j < 16; ++j) s[j] += v[j].x + v[j].y;
#pragma unroll
    for (int j = 0; j < 16; ++j) {
#pragma unroll
      for (int k = j; k < 16; ++k) {
        const int idx = j * 16 - (j * (j - 1)) / 2 + (k - j);  // const-folded
        pr[idx] += v[j].x * v[k].x + v[j].y * v[k].y;
      }
    }
  }

  __shared__ float wbuf[4][kAcc];
  const int lane = t & 63, w = t >> 6;
#pragma unroll
  for (int j = 0; j < 16; ++j) {
    float r = wave_sum64(s[j]);
    if (lane == 63) wbuf[w][j] = r;
  }
#pragma unroll
  for (int a = 0; a < 136; ++a) {
    float r = wave_sum64(pr[a]);
    if (lane == 63) wbuf[w][16 + a] = r;
  }
  __syncthreads();
  if (t < kAcc)
    partials[(size_t)p * kAcc + t] =
        (wbuf[0][t] + wbuf[1][t]) + (wbuf[2][t] + wbuf[3][t]);
}

// -------- kernel 2: reduce partials + Newton-Schulz isqrt (single block) --------
__global__ __launch_bounds__(256) void fd_newton(const float* __restrict__ partials,
                                                 float* __restrict__ params) {
  __shared__ float stats[kAcc];
  __shared__ float meanv[16];
  __shared__ float Yb[2][256];
  __shared__ float Zb[2][256];
  __shared__ float Tm[256];
  __shared__ float redb[4];
  __shared__ float snorm;
  const int t = threadIdx.x;

  if (t < kAcc) {  // 8 independent chains for MLP; deterministic order
    const float* q = partials + t;
    float a0=0,a1=0,a2=0,a3=0,a4=0,a5=0,a6=0,a7=0;
    for (int b = 0; b < kP; b += 8) {
      a0 += q[(size_t)(b+0)*kAcc]; a1 += q[(size_t)(b+1)*kAcc];
      a2 += q[(size_t)(b+2)*kAcc]; a3 += q[(size_t)(b+3)*kAcc];
      a4 += q[(size_t)(b+4)*kAcc]; a5 += q[(size_t)(b+5)*kAcc];
      a6 += q[(size_t)(b+6)*kAcc]; a7 += q[(size_t)(b+7)*kAcc];
    }
    stats[t] = ((a0+a1)+(a2+a3)) + ((a4+a5)+(a6+a7));
  }
  __syncthreads();
  constexpr float invM = 1.0f / (float)(kP * kHW);   // M = 1,605,632
  if (t < 16) meanv[t] = stats[t] * invM;
  __syncthreads();

  const int i = t >> 4, j = t & 15;
  const int a = i < j ? i : j, b = i < j ? j : i;
  float cij = stats[16 + a * 16 - (a * (a - 1)) / 2 + (b - a)] * invM
              - meanv[i] * meanv[j];
  if (i == j) cij += kEps;

  // Frobenius norm of cov
  float r = wave_sum64(cij * cij);
  if ((t & 63) == 63) redb[t >> 6] = r;
  __syncthreads();
  if (t == 0) snorm = sqrtf((redb[0] + redb[1]) + (redb[2] + redb[3]));
  __syncthreads();

  Yb[0][t] = cij * (1.0f / snorm);
  Zb[0][t] = (i == j) ? 1.0f : 0.0f;
  __syncthreads();

  int cur = 0;
  for (int it = 0; it < kNsIter; ++it) {
    float acc = 0.f;
#pragma unroll
    for (int k = 0; k < 16; ++k) acc += Zb[cur][i * 16 + k] * Yb[cur][k * 16 + j];
    Tm[t] = ((i == j) ? 1.5f : 0.0f) - 0.5f * acc;
    __syncthreads();
    float y = 0.f, z = 0.f;
#pragma unroll
    for (int k = 0; k < 16; ++k) {
      y += Yb[cur][i * 16 + k] * Tm[k * 16 + j];
      z += Tm[i * 16 + k] * Zb[cur][k * 16 + j];
    }
    Yb[cur ^ 1][t] = y;
    Zb[cur ^ 1][t] = z;
    cur ^= 1;
    __syncthreads();
  }

  const float D = Zb[cur][t] / sqrtf(snorm);  // A^{-1/2}
  params[t] = D;
  Tm[t] = D * meanv[j];
  __syncthreads();
  if (t < 16) {
    float o = 0.f;
#pragma unroll
    for (int k = 0; k < 16; ++k) o += Tm[t * 16 + k];
    params[256 + t] = o;  // offset[g] = sum_j D[g][j]*mean[j]
  }
}

// --------------- kernel 3: whitening GEMM-16 + affine (read + write) ---------------
__global__ __launch_bounds__(256, 2) void fd_whiten(const float* __restrict__ x,
                                                    const float* __restrict__ weight,
                                                    const float* __restrict__ bias,
                                                    const float* __restrict__ params,
                                                    float* __restrict__ out) {
  __shared__ __align__(16) float Dw[256];
  __shared__ float shiftv[16];
  const int p = blockIdx.x;
  const int n = p >> 4, c1 = p & 15;
  const int t = threadIdx.x;
  {
    const int g = t >> 4;
    Dw[t] = params[t] * weight[c1 * 16 + g];  // fold weight into D row g
  }
  if (t < 16) {
    const int ch = c1 * 16 + t;
    shiftv[t] = bias[ch] - params[256 + t] * weight[ch];
  }
  __syncthreads();

  const float* base  = x   + (size_t)(n * kC + c1 * 16) * kHW;
  float*       obase = out + (size_t)(n * kC + c1 * 16) * kHW;

#define FMA4(dd, vv) \
  acc.x += (dd) * (vv).x; acc.y += (dd) * (vv).y; \
  acc.z += (dd) * (vv).z; acc.w += (dd) * (vv).w;

  for (int ch4 = t; ch4 < kHW / 4; ch4 += 256) {
    float4 v[16];
#pragma unroll
    for (int j = 0; j < 16; ++j)
      v[j] = reinterpret_cast<const float4*>(base + j * kHW)[ch4];
#pragma unroll
    for (int g = 0; g < 16; ++g) {
      const float4* dr = reinterpret_cast<const float4*>(&Dw[g * 16]);
      const float sh = shiftv[g];
      float4 acc = make_float4(sh, sh, sh, sh);
#pragma unroll
      for (int j4 = 0; j4 < 4; ++j4) {
        const float4 d = dr[j4];  // LDS broadcast read (ds_read_b128)
        FMA4(d.x, v[4 * j4 + 0]);
        FMA4(d.y, v[4 * j4 + 1]);
        FMA4(d.z, v[4 * j4 + 2]);
        FMA4(d.w, v[4 * j4 + 3]);
      }
      reinterpret_cast<float4*>(obase + g * kHW)[ch4] = acc;
    }
  }
#undef FMA4
}

extern "C" void kernel_launch(void* const* d_in, const int* in_sizes, int n_in,
                              void* d_out, int out_size, void* d_ws, size_t ws_size,
                              hipStream_t stream) {
  const float* x      = (const float*)d_in[0];
  const float* weight = (const float*)d_in[1];
  const float* bias   = (const float*)d_in[2];
  float* out = (float*)d_out;

  float* wsf      = (float*)d_ws;
  float* partials = wsf;                        // kP * kAcc floats (written every call)
  float* params   = wsf + (size_t)kP * kAcc;    // 256 (D) + 16 (offset)

  fd_stats <<<kP, 256, 0, stream>>>(x, partials);
  fd_newton<<<1,  256, 0, stream>>>(partials, params);
  fd_whiten<<<kP, 256, 0, stream>>>(x, weight, bias, params, out);
}

// Round 7
// 94.349 us; speedup vs baseline: 4.1444x; 4.1444x over previous
//
#include <hip/hip_runtime.h>

// FeatureDecorr: group whitening via Newton-Schulz isqrt of 16x16 group covariance.
// x: (32, 256, 56, 56) fp32. Group g = c % 16; "plane-set" p = (n, c/16): 16
// contiguous channel planes of 3136 floats each.
//
//  1) fd_stats:  one read of x -> per-block partial {16 sums, 136 upper-tri products}
//  2) fd_newton: reduce partials, cov = S2/M - mean mean^T + eps I, NS-10, emit D/offset
//  3) fd_whiten: wave owns 4 output planes; D rows in SGPRs; nontemporal stores

constexpr int kC    = 256;
constexpr int kHW   = 3136;   // 56*56
constexpr int kP    = 512;    // N * (C/G) = 32*16 plane-sets
constexpr int kAcc  = 152;    // 16 sums + 136 upper-tri products
constexpr float kEps = 1e-5f;
constexpr int kNsIter = 10;
constexpr int kSplit = 4;     // spatial split of whiten: 784 float4 = 4 x 196
constexpr int kChunk = 196;   // float4 positions per block

// native clang vector for nontemporal builtin (HIP float4 is a class type)
typedef float floatx4 __attribute__((ext_vector_type(4)));

// ---- DPP wave64 float sum (VALU-rate) ----
template <int Ctrl, int RowMask>
__device__ __forceinline__ float dpp_fadd(float x) {
  int perm = __builtin_amdgcn_update_dpp(0, __float_as_int(x), Ctrl, RowMask, 0xf, true);
  return x + __int_as_float(perm);
}
__device__ __forceinline__ float wave_sum64(float x) {
  x = dpp_fadd<0xB1, 0xF>(x);   // quad_perm xor1
  x = dpp_fadd<0x4E, 0xF>(x);   // quad_perm xor2
  x = dpp_fadd<0x124, 0xF>(x);  // row_ror:4
  x = dpp_fadd<0x128, 0xF>(x);  // row_ror:8
  x = dpp_fadd<0x142, 0xA>(x);  // row_bcast15
  x = dpp_fadd<0x143, 0xC>(x);  // row_bcast31 -> lane 63 = full sum
  return x;
}

// ---------------- kernel 1: statistics (unchanged control) ----------------
__global__ __launch_bounds__(256, 2) void fd_stats(const float* __restrict__ x,
                                                   float* __restrict__ partials) {
  const int p  = blockIdx.x;
  const int n  = p >> 4, c1 = p & 15;
  const float* base = x + (size_t)(n * kC + c1 * 16) * kHW;
  const int t = threadIdx.x;

  float s[16];
  float pr[136];
#pragma unroll
  for (int j = 0; j < 16; ++j) s[j] = 0.f;
#pragma unroll
  for (int a = 0; a < 136; ++a) pr[a] = 0.f;

  for (int ch = t; ch < kHW / 2; ch += 256) {
    float2 v[16];
#pragma unroll
    for (int j = 0; j < 16; ++j)
      v[j] = reinterpret_cast<const float2*>(base + j * kHW)[ch];
#pragma unroll
    for (int j = 0; j < 16; ++j) s[j] += v[j].x + v[j].y;
#pragma unroll
    for (int j = 0; j < 16; ++j) {
#pragma unroll
      for (int k = j; k < 16; ++k) {
        const int idx = j * 16 - (j * (j - 1)) / 2 + (k - j);
        pr[idx] += v[j].x * v[k].x + v[j].y * v[k].y;
      }
    }
  }

  __shared__ float wbuf[4][kAcc];
  const int lane = t & 63, w = t >> 6;
#pragma unroll
  for (int j = 0; j < 16; ++j) {
    float r = wave_sum64(s[j]);
    if (lane == 63) wbuf[w][j] = r;
  }
#pragma unroll
  for (int a = 0; a < 136; ++a) {
    float r = wave_sum64(pr[a]);
    if (lane == 63) wbuf[w][16 + a] = r;
  }
  __syncthreads();
  if (t < kAcc)
    partials[(size_t)p * kAcc + t] =
        (wbuf[0][t] + wbuf[1][t]) + (wbuf[2][t] + wbuf[3][t]);
}

// -------- kernel 2: reduce partials + Newton-Schulz (unchanged control) --------
__global__ __launch_bounds__(256) void fd_newton(const float* __restrict__ partials,
                                                 float* __restrict__ params) {
  __shared__ float stats[kAcc];
  __shared__ float meanv[16];
  __shared__ float Yb[2][256];
  __shared__ float Zb[2][256];
  __shared__ float Tm[256];
  __shared__ float redb[4];
  __shared__ float snorm;
  const int t = threadIdx.x;

  if (t < kAcc) {
    const float* q = partials + t;
    float a0=0,a1=0,a2=0,a3=0,a4=0,a5=0,a6=0,a7=0;
    for (int b = 0; b < kP; b += 8) {
      a0 += q[(size_t)(b+0)*kAcc]; a1 += q[(size_t)(b+1)*kAcc];
      a2 += q[(size_t)(b+2)*kAcc]; a3 += q[(size_t)(b+3)*kAcc];
      a4 += q[(size_t)(b+4)*kAcc]; a5 += q[(size_t)(b+5)*kAcc];
      a6 += q[(size_t)(b+6)*kAcc]; a7 += q[(size_t)(b+7)*kAcc];
    }
    stats[t] = ((a0+a1)+(a2+a3)) + ((a4+a5)+(a6+a7));
  }
  __syncthreads();
  constexpr float invM = 1.0f / (float)(kP * kHW);
  if (t < 16) meanv[t] = stats[t] * invM;
  __syncthreads();

  const int i = t >> 4, j = t & 15;
  const int a = i < j ? i : j, b = i < j ? j : i;
  float cij = stats[16 + a * 16 - (a * (a - 1)) / 2 + (b - a)] * invM
              - meanv[i] * meanv[j];
  if (i == j) cij += kEps;

  float r = wave_sum64(cij * cij);
  if ((t & 63) == 63) redb[t >> 6] = r;
  __syncthreads();
  if (t == 0) snorm = sqrtf((redb[0] + redb[1]) + (redb[2] + redb[3]));
  __syncthreads();

  Yb[0][t] = cij * (1.0f / snorm);
  Zb[0][t] = (i == j) ? 1.0f : 0.0f;
  __syncthreads();

  int cur = 0;
  for (int it = 0; it < kNsIter; ++it) {
    float acc = 0.f;
#pragma unroll
    for (int k = 0; k < 16; ++k) acc += Zb[cur][i * 16 + k] * Yb[cur][k * 16 + j];
    Tm[t] = ((i == j) ? 1.5f : 0.0f) - 0.5f * acc;
    __syncthreads();
    float y = 0.f, z = 0.f;
#pragma unroll
    for (int k = 0; k < 16; ++k) {
      y += Yb[cur][i * 16 + k] * Tm[k * 16 + j];
      z += Tm[i * 16 + k] * Zb[cur][k * 16 + j];
    }
    Yb[cur ^ 1][t] = y;
    Zb[cur ^ 1][t] = z;
    cur ^= 1;
    __syncthreads();
  }

  const float D = Zb[cur][t] / sqrtf(snorm);
  params[t] = D;
  Tm[t] = D * meanv[j];
  __syncthreads();
  if (t < 16) {
    float o = 0.f;
#pragma unroll
    for (int k = 0; k < 16; ++k) o += Tm[t * 16 + k];
    params[256 + t] = o;  // offset[g] = sum_j D[g][j]*mean[j]
  }
}

// --------------- kernel 3: whitening, wave-per-4-planes restructure ---------------
// grid = kP * kSplit blocks; block = 256 thr = 4 waves; wave w computes output
// planes g in [4w, 4w+4) for kChunk float4-positions. D rows live in SGPRs
// (wave-uniform s_load), so per-thread state is ~24 VGPR: acc[4] + v + addr.
__global__ __launch_bounds__(256, 4) void fd_whiten(const float* __restrict__ x,
                                                    const float* __restrict__ weight,
                                                    const float* __restrict__ bias,
                                                    const float* __restrict__ params,
                                                    float* __restrict__ out) {
  const int blk = blockIdx.x;
  const int p = blk >> 2, s = blk & (kSplit - 1);
  const int n = p >> 4, c1 = p & 15;
  const int t = threadIdx.x;
  // Force wave-uniformity so D-row reads become scalar loads.
  const int w    = __builtin_amdgcn_readfirstlane(t >> 6);
  const int lane = t & 63;
  const int g0   = 4 * w;

  const float* base  = x   + (size_t)(n * kC + c1 * 16) * kHW;
  float*       obase = out + (size_t)(n * kC + c1 * 16) * kHW;

  // D rows for this wave (uniform address -> s_load), plus per-plane scale/shift.
  float d[4][16];
#pragma unroll
  for (int gg = 0; gg < 4; ++gg)
#pragma unroll
    for (int j = 0; j < 16; ++j)
      d[gg][j] = params[(g0 + gg) * 16 + j];

  float wv[4], sv[4];
#pragma unroll
  for (int gg = 0; gg < 4; ++gg) {
    const int g  = g0 + gg;
    const int ch = c1 * 16 + g;
    wv[gg] = weight[ch];
    sv[gg] = bias[ch] - params[256 + g] * wv[gg];  // bias - w * (D@mean)
  }

  // kChunk float4-positions per block, strided by 64 within the wave.
  for (int lp = lane; lp < kChunk; lp += 64) {
    const int pos = s * kChunk + lp;
    float4 acc0 = make_float4(0.f, 0.f, 0.f, 0.f);
    float4 acc1 = acc0, acc2 = acc0, acc3 = acc0;
#pragma unroll
    for (int j = 0; j < 16; ++j) {
      const float4 v = reinterpret_cast<const float4*>(base + j * kHW)[pos];
#define ACC(A, dd) A.x += (dd) * v.x; A.y += (dd) * v.y; A.z += (dd) * v.z; A.w += (dd) * v.w;
      ACC(acc0, d[0][j]); ACC(acc1, d[1][j]); ACC(acc2, d[2][j]); ACC(acc3, d[3][j]);
#undef ACC
    }
#define EMIT(A, gg)                                                          \
    {                                                                        \
      floatx4 o;                                                             \
      o.x = A.x * wv[gg] + sv[gg]; o.y = A.y * wv[gg] + sv[gg];              \
      o.z = A.z * wv[gg] + sv[gg]; o.w = A.w * wv[gg] + sv[gg];              \
      __builtin_nontemporal_store(                                           \
          o, reinterpret_cast<floatx4*>(obase + (g0 + gg) * kHW) + pos);     \
    }
    EMIT(acc0, 0) EMIT(acc1, 1) EMIT(acc2, 2) EMIT(acc3, 3)
#undef EMIT
  }
}

extern "C" void kernel_launch(void* const* d_in, const int* in_sizes, int n_in,
                              void* d_out, int out_size, void* d_ws, size_t ws_size,
                              hipStream_t stream) {
  const float* x      = (const float*)d_in[0];
  const float* weight = (const float*)d_in[1];
  const float* bias   = (const float*)d_in[2];
  float* out = (float*)d_out;

  float* wsf      = (float*)d_ws;
  float* partials = wsf;                        // kP * kAcc floats (written every call)
  float* params   = wsf + (size_t)kP * kAcc;    // 256 (D) + 16 (offset)

  fd_stats <<<kP, 256, 0, stream>>>(x, partials);
  fd_newton<<<1,  256, 0, stream>>>(partials, params);
  fd_whiten<<<kP * kSplit, 256, 0, stream>>>(x, weight, bias, params, out);
}